// Round 1
// baseline (867.203 us; speedup 1.0000x reference)
//
#include <hip/hip_runtime.h>
#include <hip/hip_bf16.h>
#include <cstdint>
#include <cstddef>

using bf16 = __hip_bfloat16;

typedef __attribute__((ext_vector_type(4))) float f32x4;
typedef __attribute__((ext_vector_type(8))) short s16x8;

#define LSEQ 4096
#define DDIM 512
#define KFLT 24
#define NFFT 8192
#define FPAD 4224            // padded frequency count (4097 live)
#define MROWS 8448           // 2*FPAD interleaved re/im rows
#define FLIVE 8194           // 2*4097 live rows
#define TWO_PI_OVER_N 7.669903939428206e-4f

__device__ __forceinline__ void gld16(const bf16* g, bf16* l) {
  __builtin_amdgcn_global_load_lds((const __attribute__((address_space(1))) void*)g,
                                   (__attribute__((address_space(3))) void*)l, 16, 0, 0);
}

// -------- transpose + f32->bf16 cast: out[c][r] = bf16(in[r][c]), batched over z
__global__ __launch_bounds__(256) void transpose_cast(
    const float* __restrict__ in, bf16* __restrict__ out, int R, int C) {
  __shared__ float tile[32][33];
  const size_t bo = (size_t)blockIdx.z * R * C;
  const float* inb = in + bo;
  bf16* outb = out + bo;
  int c0 = blockIdx.x * 32, r0 = blockIdx.y * 32;
  int tx = threadIdx.x & 31, ty = threadIdx.x >> 5;   // 256 thr: ty 0..7
  #pragma unroll
  for (int i = 0; i < 32; i += 8)
    tile[ty + i][tx] = inb[(size_t)(r0 + ty + i) * C + (c0 + tx)];
  __syncthreads();
  #pragma unroll
  for (int i = 0; i < 32; i += 8)
    outb[(size_t)(c0 + ty + i) * R + (r0 + tx)] = __float2bfloat16(tile[tx][ty + i]);
}

// -------- forward-DFT matrix, interleaved rows: W[2f][t]=cos(2pi f t/N), W[2f+1][t]=-sin
__global__ __launch_bounds__(256) void gen_w(bf16* __restrict__ W) {
  int r = blockIdx.y;                       // 0..8447
  int t = blockIdx.x * 256 + threadIdx.x;   // 0..4095
  float v = 0.f;
  if (r < FLIVE) {
    int f = r >> 1;
    int m = (f * t) & (NFFT - 1);           // exact integer phase
    float s, c;
    __sincosf((float)m * TWO_PI_OVER_N, &s, &c);
    v = (r & 1) ? -s : c;
  }
  W[(size_t)r * LSEQ + t] = __float2bfloat16(v);
}

// -------- inverse-DFT matrix: Cinv[l][2f]=wf/N*cos(2pi f l/N), Cinv[l][2f+1]=-wf/N*sin
__global__ __launch_bounds__(256) void gen_cinv(bf16* __restrict__ Cinv) {
  int l = blockIdx.y;                       // 0..4095
  int r = blockIdx.x * 256 + threadIdx.x;   // 0..8447
  float v = 0.f;
  if (r < FLIVE) {
    int f = r >> 1;
    int m = (f * l) & (NFFT - 1);
    float s, c;
    __sincosf((float)m * TWO_PI_OVER_N, &s, &c);
    float wf = (f == 0 || f == NFFT / 2) ? 1.f : 2.f;
    float scale = wf * (1.f / NFFT);
    v = (r & 1) ? -scale * s : scale * c;
  }
  Cinv[(size_t)l * MROWS + r] = __float2bfloat16(v);
}

// -------- Pf[f][k] = sum_t phi[t][k] e^{-2pi i f t/N}, stored [f][k][re,im] f32
__global__ __launch_bounds__(256) void compute_pf(
    const float* __restrict__ phi, float* __restrict__ Pf) {
  int f = blockIdx.x;                       // 0..4096
  int tid = threadIdx.x;
  int lane = tid & 63, wave = tid >> 6;
  float pre[KFLT], pim[KFLT];
  #pragma unroll
  for (int k = 0; k < KFLT; ++k) { pre[k] = 0.f; pim[k] = 0.f; }
  for (int cch = 0; cch < LSEQ / 256; ++cch) {
    int t = cch * 256 + tid;
    int m = (f * t) & (NFFT - 1);
    float s, c;
    __sincosf((float)m * TWO_PI_OVER_N, &s, &c);
    const float* prow = phi + (size_t)t * KFLT;
    #pragma unroll
    for (int k = 0; k < KFLT; ++k) {
      float p = prow[k];
      pre[k] += p * c;
      pim[k] -= p * s;
    }
  }
  __shared__ float red[4][2 * KFLT];
  #pragma unroll
  for (int k = 0; k < KFLT; ++k) {
    float r = pre[k], i2 = pim[k];
    #pragma unroll
    for (int off = 32; off > 0; off >>= 1) {
      r += __shfl_down(r, off, 64);
      i2 += __shfl_down(i2, off, 64);
    }
    if (lane == 0) { red[wave][2 * k] = r; red[wave][2 * k + 1] = i2; }
  }
  __syncthreads();
  if (tid < 2 * KFLT)
    Pf[(size_t)f * (2 * KFLT) + tid] =
        red[0][tid] + red[1][tid] + red[2][tid] + red[3][tid];
}

// -------- Pw[j][f][re,im]: j<24 plus-sign = Pf[f][k]; j>=24 minus = conj(Pf[4096-f][k])
__global__ __launch_bounds__(256) void build_pw(
    const float* __restrict__ Pf, float* __restrict__ Pw) {
  int idx = blockIdx.x * 256 + threadIdx.x;
  if (idx >= 48 * FPAD) return;
  int j = idx / FPAD, f = idx % FPAD;
  float re = 0.f, im = 0.f;
  if (f <= NFFT / 2) {
    if (j < KFLT) {
      re = Pf[(size_t)f * 48 + j * 2];
      im = Pf[(size_t)f * 48 + j * 2 + 1];
    } else {
      int k = j - KFLT, g = NFFT / 2 - f;
      re = Pf[(size_t)g * 48 + k * 2];
      im = -Pf[(size_t)g * 48 + k * 2 + 1];
    }
  }
  Pw[(size_t)idx * 2] = re;
  Pw[(size_t)idx * 2 + 1] = im;
}

// -------- GEMM C = A[M,K] * Bt[N,K]^T, m97 structure: 128x128 tile, BK=64, 4 waves,
// global_load_lds(16B) staging, 16x16x32 bf16 MFMA.
// EPI 0: store bf16 C. EPI 1: complex-weight (Pw) accumulate over j, atomicAdd f32 C.
// EPI 2: store f32 C.
template <int EPI>
__global__ __launch_bounds__(256, 2) void gemm_bt(
    const bf16* __restrict__ A, const bf16* __restrict__ Bt,
    int N, int Kin,
    bf16* __restrict__ Cbf, float* __restrict__ Cf,
    const float* __restrict__ Pw, int jcount) {
  __shared__ bf16 sA[128 * 64];
  __shared__ bf16 sB[128 * 64];
  const int tid = threadIdx.x;
  const int lane = tid & 63, wave = tid >> 6;
  const int mtile = blockIdx.y * 128, ntile = blockIdx.x * 128;
  const int wr = wave >> 1, wc = wave & 1;
  const int l15 = lane & 15, l4 = lane >> 4;

  const bf16* Abase = A + (size_t)mtile * Kin;

  f32x4 yacc[4][4];
  if constexpr (EPI == 1) {
    #pragma unroll
    for (int m = 0; m < 4; ++m)
      #pragma unroll
      for (int n = 0; n < 4; ++n)
        yacc[m][n] = f32x4{0.f, 0.f, 0.f, 0.f};
  }

  const int jn = (EPI == 1) ? jcount : 1;
  for (int jj = 0; jj < jn; ++jj) {
    const int j = (EPI == 1) ? (blockIdx.z * jcount + jj) : 0;
    const bf16* Bbase = Bt + (size_t)j * DDIM * DDIM + (size_t)ntile * Kin;

    f32x4 acc[4][4];
    #pragma unroll
    for (int m = 0; m < 4; ++m)
      #pragma unroll
      for (int n = 0; n < 4; ++n)
        acc[m][n] = f32x4{0.f, 0.f, 0.f, 0.f};

    for (int k0 = 0; k0 < Kin; k0 += 64) {
      #pragma unroll
      for (int i = 0; i < 4; ++i) {
        int chunk = i * 4 + wave;              // 0..15, wave-uniform
        int row = chunk * 8 + (lane >> 3);     // 0..127
        int colE = (lane & 7) * 8;
        gld16(Abase + (size_t)row * Kin + (k0 + colE), sA + chunk * 512);
        gld16(Bbase + (size_t)row * Kin + (k0 + colE), sB + chunk * 512);
      }
      __syncthreads();
      #pragma unroll
      for (int kk = 0; kk < 2; ++kk) {
        s16x8 af[4], bfv[4];
        #pragma unroll
        for (int m = 0; m < 4; ++m)
          af[m] = *(const s16x8*)(sA + (wr * 64 + m * 16 + l15) * 64 + kk * 32 + l4 * 8);
        #pragma unroll
        for (int n = 0; n < 4; ++n)
          bfv[n] = *(const s16x8*)(sB + (wc * 64 + n * 16 + l15) * 64 + kk * 32 + l4 * 8);
        #pragma unroll
        for (int m = 0; m < 4; ++m)
          #pragma unroll
          for (int n = 0; n < 4; ++n)
            acc[m][n] = __builtin_amdgcn_mfma_f32_16x16x32_bf16(
                af[m], bfv[n], acc[m][n], 0, 0, 0);
      }
      __syncthreads();
    }

    if constexpr (EPI == 1) {
      // rows rbase+0..3 are (re,im) pairs of freqs f, f+1 -> register-local complex mul
      #pragma unroll
      for (int m = 0; m < 4; ++m) {
        int rbase = mtile + wr * 64 + m * 16 + l4 * 4;   // even
        #pragma unroll
        for (int p = 0; p < 2; ++p) {
          int f = (rbase >> 1) + p;
          float2 w = *(const float2*)(Pw + ((size_t)j * FPAD + f) * 2);
          #pragma unroll
          for (int n = 0; n < 4; ++n) {
            float vre = acc[m][n][2 * p], vim = acc[m][n][2 * p + 1];
            yacc[m][n][2 * p]     += w.x * vre - w.y * vim;
            yacc[m][n][2 * p + 1] += w.x * vim + w.y * vre;
          }
        }
      }
    } else if constexpr (EPI == 0) {
      #pragma unroll
      for (int m = 0; m < 4; ++m)
        #pragma unroll
        for (int n = 0; n < 4; ++n)
          #pragma unroll
          for (int i = 0; i < 4; ++i) {
            int row = mtile + wr * 64 + m * 16 + l4 * 4 + i;
            int col = ntile + wc * 64 + n * 16 + l15;
            Cbf[(size_t)row * N + col] = __float2bfloat16(acc[m][n][i]);
          }
    } else {
      #pragma unroll
      for (int m = 0; m < 4; ++m)
        #pragma unroll
        for (int n = 0; n < 4; ++n)
          #pragma unroll
          for (int i = 0; i < 4; ++i) {
            int row = mtile + wr * 64 + m * 16 + l4 * 4 + i;
            int col = ntile + wc * 64 + n * 16 + l15;
            Cf[(size_t)row * N + col] = acc[m][n][i];
          }
    }
  }

  if constexpr (EPI == 1) {
    #pragma unroll
    for (int m = 0; m < 4; ++m)
      #pragma unroll
      for (int n = 0; n < 4; ++n)
        #pragma unroll
        for (int i = 0; i < 4; ++i) {
          int row = mtile + wr * 64 + m * 16 + l4 * 4 + i;
          int col = ntile + wc * 64 + n * 16 + l15;
          atomicAdd(&Cf[(size_t)row * N + col], yacc[m][n][i]);
        }
  }
}

// ---------------- workspace layout (bytes) ----------------
#define WS_W     0ULL                    // 8448*4096 bf16 = 69,206,016  (Wdft, later Cinv)
#define WS_AUF   69206016ULL             // 8448*512  bf16 =  8,650,752
#define WS_UT    77856768ULL             // 512*4096  bf16 =  4,194,304
#define WS_MT    82051072ULL             // 48*512*512 bf16 = 25,165,824
#define WS_PF    107216896ULL            // 4097*48 f32    =    786,624
#define WS_PW    108003520ULL            // 48*4224*2 f32  =  1,622,016
#define WS_YSUM  109625536ULL            // 8448*512 f32   = 17,301,504
#define WS_YBT   126927040ULL            // 512*8448 bf16  =  8,650,752
#define WS_TOTAL 135577792ULL

extern "C" void kernel_launch(void* const* d_in, const int* in_sizes, int n_in,
                              void* d_out, int out_size, void* d_ws, size_t ws_size,
                              hipStream_t stream) {
  const float* u   = (const float*)d_in[0];   // [4096, 512]
  const float* phi = (const float*)d_in[1];   // [4096, 24]
  const float* Mp  = (const float*)d_in[2];   // [24, 512, 512]
  const float* Mm  = (const float*)d_in[3];   // [24, 512, 512]
  float* y = (float*)d_out;                   // [4096, 512]

  if (ws_size < WS_TOTAL) return;             // loud failure: output stays zero

  char* ws = (char*)d_ws;
  bf16*  W    = (bf16*)(ws + WS_W);
  bf16*  Auf  = (bf16*)(ws + WS_AUF);
  bf16*  uT   = (bf16*)(ws + WS_UT);
  bf16*  Mt   = (bf16*)(ws + WS_MT);
  float* Pf   = (float*)(ws + WS_PF);
  float* Pw   = (float*)(ws + WS_PW);
  float* Ysum = (float*)(ws + WS_YSUM);
  bf16*  Ybt  = (bf16*)(ws + WS_YBT);

  // prologue: transposed bf16 operands + spectral weight tables
  transpose_cast<<<dim3(16, 128, 1), 256, 0, stream>>>(u, uT, LSEQ, DDIM);
  transpose_cast<<<dim3(16, 16, 24), 256, 0, stream>>>(Mp, Mt, DDIM, DDIM);
  transpose_cast<<<dim3(16, 16, 24), 256, 0, stream>>>(Mm, Mt + (size_t)24 * DDIM * DDIM,
                                                       DDIM, DDIM);
  gen_w<<<dim3(16, MROWS), 256, 0, stream>>>(W);
  compute_pf<<<dim3(4097), 256, 0, stream>>>(phi, Pf);
  build_pw<<<dim3((48 * FPAD + 255) / 256), 256, 0, stream>>>(Pf, Pw);

  // G1: uf (interleaved re/im rows) = Wdft @ u
  gemm_bt<0><<<dim3(4, 66, 1), 256, 0, stream>>>(W, uT, DDIM, LSEQ, Auf, nullptr,
                                                 nullptr, 1);

  // G2: Ysum = sum_j Pw[j] .* (uf @ M_j)   (48 j = 24 k x 2 signs; z-groups of 8)
  hipMemsetAsync(Ysum, 0, (size_t)MROWS * DDIM * sizeof(float), stream);
  gemm_bt<1><<<dim3(4, 66, 6), 256, 0, stream>>>(Auf, Mt, DDIM, DDIM, nullptr, Ysum,
                                                 Pw, 8);

  // G3: y = Cinv @ Ysum   (Cinv overwrites the Wdft buffer; Ysum transposed+cast first)
  gen_cinv<<<dim3(33, LSEQ), 256, 0, stream>>>(W);
  transpose_cast<<<dim3(16, 264, 1), 256, 0, stream>>>(Ysum, Ybt, MROWS, DDIM);
  gemm_bt<2><<<dim3(4, 32, 1), 256, 0, stream>>>(W, Ybt, DDIM, MROWS, nullptr, y,
                                                 nullptr, 1);
}

// Round 2
// 823.048 us; speedup vs baseline: 1.0536x; 1.0536x over previous
//
#include <hip/hip_runtime.h>
#include <hip/hip_bf16.h>
#include <cstdint>
#include <cstddef>

using bf16 = __hip_bfloat16;

typedef __attribute__((ext_vector_type(4))) float f32x4;
typedef __attribute__((ext_vector_type(8))) short s16x8;

#define LSEQ 4096
#define DDIM 512
#define KFLT 24
#define NFFT 8192
#define FPAD 4224            // padded frequency count (4097 live)
#define MROWS 8448           // 2*FPAD interleaved re/im rows
#define FLIVE 8194           // 2*4097 live rows
#define TWO_PI_OVER_N 7.669903939428206e-4f

__device__ __forceinline__ void gld16(const bf16* g, bf16* l) {
  __builtin_amdgcn_global_load_lds((const __attribute__((address_space(1))) void*)g,
                                   (__attribute__((address_space(3))) void*)l, 16, 0, 0);
}

// -------- transpose + cast->bf16: out[c][r] = bf16(in[r][c]), batched over z
__global__ __launch_bounds__(256) void transpose_cast(
    const float* __restrict__ in, bf16* __restrict__ out, int R, int C) {
  __shared__ float tile[32][33];
  const size_t bo = (size_t)blockIdx.z * R * C;
  const float* inb = in + bo;
  bf16* outb = out + bo;
  int c0 = blockIdx.x * 32, r0 = blockIdx.y * 32;
  int tx = threadIdx.x & 31, ty = threadIdx.x >> 5;   // 256 thr: ty 0..7
  #pragma unroll
  for (int i = 0; i < 32; i += 8)
    tile[ty + i][tx] = inb[(size_t)(r0 + ty + i) * C + (c0 + tx)];
  __syncthreads();
  #pragma unroll
  for (int i = 0; i < 32; i += 8)
    outb[(size_t)(c0 + ty + i) * R + (r0 + tx)] = __float2bfloat16(tile[tx][ty + i]);
}

// -------- elementwise f32 -> bf16 cast, 8 elems/thread
__global__ __launch_bounds__(256) void cast_f32_bf16(
    const float* __restrict__ in, bf16* __restrict__ out, int n) {
  int i = (blockIdx.x * 256 + threadIdx.x) * 8;
  if (i >= n) return;
  const float4 a = *(const float4*)(in + i);
  const float4 b = *(const float4*)(in + i + 4);
  bf16 o[8] = {__float2bfloat16(a.x), __float2bfloat16(a.y),
               __float2bfloat16(a.z), __float2bfloat16(a.w),
               __float2bfloat16(b.x), __float2bfloat16(b.y),
               __float2bfloat16(b.z), __float2bfloat16(b.w)};
  *(s16x8*)(out + i) = *(const s16x8*)o;
}

// -------- forward-DFT matrix, interleaved rows: W[2f][t]=cos(2pi f t/N), W[2f+1][t]=-sin
__global__ __launch_bounds__(256) void gen_w(bf16* __restrict__ W) {
  int r = blockIdx.y;                       // 0..8447
  int t = blockIdx.x * 256 + threadIdx.x;   // 0..4095
  float v = 0.f;
  if (r < FLIVE) {
    int f = r >> 1;
    int m = (f * t) & (NFFT - 1);           // exact integer phase
    float s, c;
    __sincosf((float)m * TWO_PI_OVER_N, &s, &c);
    v = (r & 1) ? -s : c;
  }
  W[(size_t)r * LSEQ + t] = __float2bfloat16(v);
}

// -------- inverse-DFT matrix: Cinv[l][2f]=wf/N*cos(2pi f l/N), Cinv[l][2f+1]=-wf/N*sin
__global__ __launch_bounds__(256) void gen_cinv(bf16* __restrict__ Cinv) {
  int l = blockIdx.y;                       // 0..4095
  int r = blockIdx.x * 256 + threadIdx.x;   // 0..8447
  float v = 0.f;
  if (r < FLIVE) {
    int f = r >> 1;
    int m = (f * l) & (NFFT - 1);
    float s, c;
    __sincosf((float)m * TWO_PI_OVER_N, &s, &c);
    float wf = (f == 0 || f == NFFT / 2) ? 1.f : 2.f;
    float scale = wf * (1.f / NFFT);
    v = (r & 1) ? -scale * s : scale * c;
  }
  Cinv[(size_t)l * MROWS + r] = __float2bfloat16(v);
}

// -------- Pf[f][k] = sum_t phi[t][k] e^{-2pi i f t/N}, stored [f][k][re,im] f32
__global__ __launch_bounds__(256) void compute_pf(
    const float* __restrict__ phi, float* __restrict__ Pf) {
  int f = blockIdx.x;                       // 0..4096
  int tid = threadIdx.x;
  int lane = tid & 63, wave = tid >> 6;
  float pre[KFLT], pim[KFLT];
  #pragma unroll
  for (int k = 0; k < KFLT; ++k) { pre[k] = 0.f; pim[k] = 0.f; }
  for (int cch = 0; cch < LSEQ / 256; ++cch) {
    int t = cch * 256 + tid;
    int m = (f * t) & (NFFT - 1);
    float s, c;
    __sincosf((float)m * TWO_PI_OVER_N, &s, &c);
    const float* prow = phi + (size_t)t * KFLT;
    #pragma unroll
    for (int k = 0; k < KFLT; ++k) {
      float p = prow[k];
      pre[k] += p * c;
      pim[k] -= p * s;
    }
  }
  __shared__ float red[4][2 * KFLT];
  #pragma unroll
  for (int k = 0; k < KFLT; ++k) {
    float r = pre[k], i2 = pim[k];
    #pragma unroll
    for (int off = 32; off > 0; off >>= 1) {
      r += __shfl_down(r, off, 64);
      i2 += __shfl_down(i2, off, 64);
    }
    if (lane == 0) { red[wave][2 * k] = r; red[wave][2 * k + 1] = i2; }
  }
  __syncthreads();
  if (tid < 2 * KFLT)
    Pf[(size_t)f * (2 * KFLT) + tid] =
        red[0][tid] + red[1][tid] + red[2][tid] + red[3][tid];
}

// -------- Pw[j][f][re,im]: j<24 plus-sign = Pf[f][k]; j>=24 minus = conj(Pf[4096-f][k])
__global__ __launch_bounds__(256) void build_pw(
    const float* __restrict__ Pf, float* __restrict__ Pw) {
  int idx = blockIdx.x * 256 + threadIdx.x;
  if (idx >= 48 * FPAD) return;
  int j = idx / FPAD, f = idx % FPAD;
  float re = 0.f, im = 0.f;
  if (f <= NFFT / 2) {
    if (j < KFLT) {
      re = Pf[(size_t)f * 48 + j * 2];
      im = Pf[(size_t)f * 48 + j * 2 + 1];
    } else {
      int k = j - KFLT, g = NFFT / 2 - f;
      re = Pf[(size_t)g * 48 + k * 2];
      im = -Pf[(size_t)g * 48 + k * 2 + 1];
    }
  }
  Pw[(size_t)idx * 2] = re;
  Pw[(size_t)idx * 2 + 1] = im;
}

// -------- GEMM C = A[M,K] * Bt[N,K]^T, m97 structure: 128x128 tile, BK=64, 4 waves,
// global_load_lds(16B) staging, 16x16x32 bf16 MFMA, bijective XCD block swizzle (m204).
// EPI 1: complex-weight (Pw) accumulate over j-group (blockIdx.z), atomicAdd f32 C.
// EPI 3: split-K over blockIdx.z, plain atomicAdd f32 C.
template <int EPI>
__global__ __launch_bounds__(256, 2) void gemm_bt(
    const bf16* __restrict__ A, const bf16* __restrict__ Bt,
    int N, int Kin, float* __restrict__ Cf,
    const float* __restrict__ Pw, int jcount) {
  // ---- bijective XCD-aware swizzle: contiguous work chunks per XCD
  const int gx = gridDim.x, gy = gridDim.y;
  const int nwg = gx * gy * gridDim.z;
  const int lin = blockIdx.x + gx * (blockIdx.y + gy * blockIdx.z);
  const int q = nwg >> 3, r8 = nwg & 7;
  const int xcd = lin & 7, pos = lin >> 3;
  const int wid = (xcd < r8 ? xcd * (q + 1) : r8 * (q + 1) + (xcd - r8) * q) + pos;
  const int bx = wid % gx;
  const int tmp = wid / gx;
  const int by = tmp % gy, bz = tmp / gy;

  __shared__ bf16 sA[128 * 64];
  __shared__ bf16 sB[128 * 64];
  const int tid = threadIdx.x;
  const int lane = tid & 63, wave = tid >> 6;
  const int mtile = by * 128, ntile = bx * 128;
  const int wr = wave >> 1, wc = wave & 1;
  const int l15 = lane & 15, l4 = lane >> 4;

  const bf16* Abase = A + (size_t)mtile * Kin;

  // split-K bounds (EPI==3): z splits the k0 loop; EPI==1 always full K
  int kbeg = 0, kend = Kin;
  if constexpr (EPI == 3) {
    const int kper = (Kin >> 6) / gridDim.z;   // k0-steps per split (exact divisor)
    kbeg = bz * kper * 64;
    kend = kbeg + kper * 64;
  }

  f32x4 yacc[4][4];
  if constexpr (EPI == 1) {
    #pragma unroll
    for (int m = 0; m < 4; ++m)
      #pragma unroll
      for (int n = 0; n < 4; ++n)
        yacc[m][n] = f32x4{0.f, 0.f, 0.f, 0.f};
  }

  const int jn = (EPI == 1) ? jcount : 1;
  for (int jj = 0; jj < jn; ++jj) {
    const int j = (EPI == 1) ? (bz * jcount + jj) : 0;
    const bf16* Bbase = Bt + (EPI == 1 ? (size_t)j * DDIM * DDIM : 0)
                        + (size_t)ntile * Kin;

    f32x4 acc[4][4];
    #pragma unroll
    for (int m = 0; m < 4; ++m)
      #pragma unroll
      for (int n = 0; n < 4; ++n)
        acc[m][n] = f32x4{0.f, 0.f, 0.f, 0.f};

    for (int k0 = kbeg; k0 < kend; k0 += 64) {
      #pragma unroll
      for (int i = 0; i < 4; ++i) {
        int chunk = i * 4 + wave;              // 0..15, wave-uniform
        int row = chunk * 8 + (lane >> 3);     // 0..127
        int colE = (lane & 7) * 8;
        gld16(Abase + (size_t)row * Kin + (k0 + colE), sA + chunk * 512);
        gld16(Bbase + (size_t)row * Kin + (k0 + colE), sB + chunk * 512);
      }
      __syncthreads();
      #pragma unroll
      for (int kk = 0; kk < 2; ++kk) {
        s16x8 af[4], bfv[4];
        #pragma unroll
        for (int m = 0; m < 4; ++m)
          af[m] = *(const s16x8*)(sA + (wr * 64 + m * 16 + l15) * 64 + kk * 32 + l4 * 8);
        #pragma unroll
        for (int n = 0; n < 4; ++n)
          bfv[n] = *(const s16x8*)(sB + (wc * 64 + n * 16 + l15) * 64 + kk * 32 + l4 * 8);
        #pragma unroll
        for (int m = 0; m < 4; ++m)
          #pragma unroll
          for (int n = 0; n < 4; ++n)
            acc[m][n] = __builtin_amdgcn_mfma_f32_16x16x32_bf16(
                af[m], bfv[n], acc[m][n], 0, 0, 0);
      }
      __syncthreads();
    }

    if constexpr (EPI == 1) {
      // rows rbase+0..3 are (re,im) pairs of freqs f, f+1 -> register-local complex mul
      #pragma unroll
      for (int m = 0; m < 4; ++m) {
        int rbase = mtile + wr * 64 + m * 16 + l4 * 4;   // even
        #pragma unroll
        for (int p = 0; p < 2; ++p) {
          int f = (rbase >> 1) + p;
          float2 w = *(const float2*)(Pw + ((size_t)j * FPAD + f) * 2);
          #pragma unroll
          for (int n = 0; n < 4; ++n) {
            float vre = acc[m][n][2 * p], vim = acc[m][n][2 * p + 1];
            yacc[m][n][2 * p]     += w.x * vre - w.y * vim;
            yacc[m][n][2 * p + 1] += w.x * vim + w.y * vre;
          }
        }
      }
    } else {
      #pragma unroll
      for (int m = 0; m < 4; ++m)
        #pragma unroll
        for (int n = 0; n < 4; ++n)
          #pragma unroll
          for (int i = 0; i < 4; ++i) {
            int row = mtile + wr * 64 + m * 16 + l4 * 4 + i;
            int col = ntile + wc * 64 + n * 16 + l15;
            atomicAdd(&Cf[(size_t)row * N + col], acc[m][n][i]);
          }
    }
  }

  if constexpr (EPI == 1) {
    #pragma unroll
    for (int m = 0; m < 4; ++m)
      #pragma unroll
      for (int n = 0; n < 4; ++n)
        #pragma unroll
        for (int i = 0; i < 4; ++i) {
          int row = mtile + wr * 64 + m * 16 + l4 * 4 + i;
          int col = ntile + wc * 64 + n * 16 + l15;
          atomicAdd(&Cf[(size_t)row * N + col], yacc[m][n][i]);
        }
  }
}

// ---------------- workspace layout (bytes) ----------------
#define WS_W     0ULL                    // 8448*4096 bf16 = 69,206,016  (Wdft, later Cinv)
#define WS_AUF   69206016ULL             // 8448*512  bf16 =  8,650,752
#define WS_UT    77856768ULL             // 512*4096  bf16 =  4,194,304
#define WS_MT    82051072ULL             // 48*512*512 bf16 = 25,165,824
#define WS_PF    107216896ULL            // 4097*48 f32    =    786,624
#define WS_PW    108003520ULL            // 48*4224*2 f32  =  1,622,016
#define WS_YSUM  109625536ULL            // 8448*512 f32   = 17,301,504
#define WS_YBT   126927040ULL            // 512*8448 bf16  =  8,650,752
#define WS_TOTAL 135577792ULL

extern "C" void kernel_launch(void* const* d_in, const int* in_sizes, int n_in,
                              void* d_out, int out_size, void* d_ws, size_t ws_size,
                              hipStream_t stream) {
  const float* u   = (const float*)d_in[0];   // [4096, 512]
  const float* phi = (const float*)d_in[1];   // [4096, 24]
  const float* Mp  = (const float*)d_in[2];   // [24, 512, 512]
  const float* Mm  = (const float*)d_in[3];   // [24, 512, 512]
  float* y = (float*)d_out;                   // [4096, 512]

  if (ws_size < WS_TOTAL) return;             // loud failure: output stays zero

  char* ws = (char*)d_ws;
  bf16*  W    = (bf16*)(ws + WS_W);
  bf16*  Auf  = (bf16*)(ws + WS_AUF);
  bf16*  uT   = (bf16*)(ws + WS_UT);
  bf16*  Mt   = (bf16*)(ws + WS_MT);
  float* Pf   = (float*)(ws + WS_PF);
  float* Pw   = (float*)(ws + WS_PW);
  float* Ysum = (float*)(ws + WS_YSUM);
  bf16*  Ybt  = (bf16*)(ws + WS_YBT);

  // prologue: transposed bf16 operands + spectral weight tables
  transpose_cast<<<dim3(16, 128, 1), 256, 0, stream>>>(u, uT, LSEQ, DDIM);
  transpose_cast<<<dim3(16, 16, 24), 256, 0, stream>>>(Mp, Mt, DDIM, DDIM);
  transpose_cast<<<dim3(16, 16, 24), 256, 0, stream>>>(Mm, Mt + (size_t)24 * DDIM * DDIM,
                                                       DDIM, DDIM);
  gen_w<<<dim3(16, MROWS), 256, 0, stream>>>(W);
  compute_pf<<<dim3(4097), 256, 0, stream>>>(phi, Pf);
  build_pw<<<dim3((48 * FPAD + 255) / 256), 256, 0, stream>>>(Pf, Pw);

  // G1: uf (interleaved re/im rows) = Wdft @ u   — split-K x4 into f32 Ysum, then cast
  hipMemsetAsync(Ysum, 0, (size_t)MROWS * DDIM * sizeof(float), stream);
  gemm_bt<3><<<dim3(4, 66, 4), 256, 0, stream>>>(W, uT, DDIM, LSEQ, Ysum, nullptr, 1);
  cast_f32_bf16<<<dim3(MROWS * DDIM / (256 * 8)), 256, 0, stream>>>(
      Ysum, Auf, MROWS * DDIM);

  // G2: Ysum = sum_j Pw[j] .* (uf @ M_j)   (48 j = 24 k x 2 signs; z-groups of 8)
  hipMemsetAsync(Ysum, 0, (size_t)MROWS * DDIM * sizeof(float), stream);
  gemm_bt<1><<<dim3(4, 66, 6), 256, 0, stream>>>(Auf, Mt, DDIM, DDIM, Ysum, Pw, 8);

  // G3: y = Cinv @ Ysum  — split-K x6 atomic into y (Cinv overwrites the Wdft buffer)
  gen_cinv<<<dim3(33, LSEQ), 256, 0, stream>>>(W);
  transpose_cast<<<dim3(16, 264, 1), 256, 0, stream>>>(Ysum, Ybt, MROWS, DDIM);
  hipMemsetAsync(y, 0, (size_t)LSEQ * DDIM * sizeof(float), stream);
  gemm_bt<3><<<dim3(4, 32, 6), 256, 0, stream>>>(W, Ybt, DDIM, MROWS, y, nullptr, 1);
}